// Round 17
// baseline (202.282 us; speedup 1.0000x reference)
//
#include <hip/hip_runtime.h>

#define LOG2E 1.44269504088896340736f
#define QSCALE 0.18033688011112042f  // 0.125 * LOG2E, folded into Q at projection
#define MREF 16.0f                   // fixed softmax reference (log2 domain)

typedef _Float16 half8 __attribute__((ext_vector_type(8)));
typedef _Float16 half4_t __attribute__((ext_vector_type(4)));
typedef __fp16 fp16x2 __attribute__((ext_vector_type(2)));
typedef float f32x4 __attribute__((ext_vector_type(4)));
typedef float f32x16 __attribute__((ext_vector_type(16)));
typedef unsigned int u32x2 __attribute__((ext_vector_type(2)));

__device__ __forceinline__ void gld16(const void* g, void* l) {
  __builtin_amdgcn_global_load_lds(
      (const __attribute__((address_space(1))) void*)g,
      (__attribute__((address_space(3))) void*)l, 16, 0, 0);
}

// ---------------- merged prep: f32->f16 cvt (hidden+W) + f16 mask table, 1 launch ---
__global__ void prep_all(const float* __restrict__ hidden, const float* __restrict__ Wq,
                         const float* __restrict__ Wk, const float* __restrict__ Wv,
                         const float* __restrict__ mask,
                         _Float16* __restrict__ hb, _Float16* __restrict__ wqb,
                         _Float16* __restrict__ wkb, _Float16* __restrict__ wvb,
                         _Float16* __restrict__ mk16, int do_mask) {
  const int NH = 1572864, NW = 147456, NM = 2048;  // f32x4 element counts
  const int total = NH + 3 * NW + (do_mask ? NM : 0);
  int i = blockIdx.x * blockDim.x + threadIdx.x;
  int st = gridDim.x * blockDim.x;
  for (int idx = i; idx < total; idx += st) {
    if (idx < NH + 3 * NW) {
      const float* src; _Float16* dst; int off;
      if (idx < NH) { src = hidden; dst = hb; off = idx; }
      else if (idx < NH + NW) { src = Wq; dst = wqb; off = idx - NH; }
      else if (idx < NH + 2 * NW) { src = Wk; dst = wkb; off = idx - NH - NW; }
      else { src = Wv; dst = wvb; off = idx - NH - 2 * NW; }
      float4 v = reinterpret_cast<const float4*>(src)[off];
      half4_t hh;
      hh[0] = (_Float16)v.x; hh[1] = (_Float16)v.y; hh[2] = (_Float16)v.z; hh[3] = (_Float16)v.w;
      reinterpret_cast<half4_t*>(dst)[off] = hh;
    } else {
      int off = idx - NH - 3 * NW;
      float4 v = reinterpret_cast<const float4*>(mask)[off];
      half4_t hh;
      hh[0] = (_Float16)((1.0f - v.x) * (-10000.0f * LOG2E) - MREF);
      hh[1] = (_Float16)((1.0f - v.y) * (-10000.0f * LOG2E) - MREF);
      hh[2] = (_Float16)((1.0f - v.z) * (-10000.0f * LOG2E) - MREF);
      hh[3] = (_Float16)((1.0f - v.w) * (-10000.0f * LOG2E) - MREF);
      reinterpret_cast<half4_t*>(mk16)[off] = hh;
    }
  }
}

// fallback (only if ws_size too small for the dedicated mk16 region): runs after gemm
__global__ void prep_mask16(const float* __restrict__ mask, _Float16* __restrict__ mk16, int n) {
  int i = blockIdx.x * blockDim.x + threadIdx.x;
  if (i < n) mk16[i] = (_Float16)((1.0f - mask[i]) * (-10000.0f * LOG2E) - MREF);
}

// ---------------- QKV projection GEMM (XCD-swizzled mt; verified R15) ----------------
__global__ __launch_bounds__(256) void qkv_gemm(
    const _Float16* __restrict__ X,
    const _Float16* __restrict__ Wq, const _Float16* __restrict__ Wk, const _Float16* __restrict__ Wv,
    const float* __restrict__ bq, const float* __restrict__ bk, const float* __restrict__ bv,
    _Float16* __restrict__ qo, _Float16* __restrict__ ko, _Float16* __restrict__ vo) {
  __shared__ _Float16 Al[2][128 * 32];
  __shared__ _Float16 Bl[2][128 * 32];
  const int tid = threadIdx.x;
  const int lane = tid & 63, w = tid >> 6;
  const int wr = w >> 1, wc = w & 1;
  const int bx = blockIdx.x;
  const int mt = (bx & 7) * 8 + (bx >> 3);  // bijective on [0,64): XCD keeps its X-panels
  const int ntl = blockIdx.y, mode = blockIdx.z;
  const _Float16* W = (mode == 0) ? Wq : (mode == 1) ? Wk : Wv;
  const float* bias = (mode == 0) ? bq : (mode == 1) ? bk : bv;
  _Float16* out = (mode == 0) ? qo : (mode == 1) ? ko : vo;
  const float oscale = (mode == 0) ? QSCALE : 1.0f;

  const _Float16* Xb = X + (size_t)mt * 128 * 768;
  const _Float16* Wb = W + (size_t)ntl * 128 * 768;

  const f32x4 zero4 = {0.f, 0.f, 0.f, 0.f};
  f32x4 acc[4][4];
#pragma unroll
  for (int i = 0; i < 4; ++i)
#pragma unroll
    for (int j = 0; j < 4; ++j) acc[i][j] = zero4;

  auto stage = [&](int bufi, int kt) {
#pragma unroll
    for (int it = 0; it < 2; ++it) {
      int ci = tid + it * 256;
      int row = ci >> 2, c = ci & 3;
      int sw = ((c ^ ((row >> 1) & 3)) << 4);
      gld16((const char*)(Xb + row * 768) + kt * 64 + sw, (char*)&Al[bufi][0] + ci * 16);
      gld16((const char*)(Wb + row * 768) + kt * 64 + sw, (char*)&Bl[bufi][0] + ci * 16);
    }
  };

  stage(0, 0);
  __syncthreads();
  int buf = 0;
  for (int kt = 0; kt < 24; ++kt) {
    if (kt + 1 < 24) stage(buf ^ 1, kt + 1);
    half8 af[4], bf[4];
#pragma unroll
    for (int mi = 0; mi < 4; ++mi) {
      int row = wr * 64 + mi * 16 + (lane & 15);
      int cc = (lane >> 4) ^ ((row >> 1) & 3);
      af[mi] = *(const half8*)((const char*)&Al[buf][0] + row * 64 + cc * 16);
    }
#pragma unroll
    for (int ni = 0; ni < 4; ++ni) {
      int row = wc * 64 + ni * 16 + (lane & 15);
      int cc = (lane >> 4) ^ ((row >> 1) & 3);
      bf[ni] = *(const half8*)((const char*)&Bl[buf][0] + row * 64 + cc * 16);
    }
#pragma unroll
    for (int mi = 0; mi < 4; ++mi)
#pragma unroll
      for (int ni = 0; ni < 4; ++ni)
        acc[mi][ni] = __builtin_amdgcn_mfma_f32_16x16x32_f16(af[mi], bf[ni], acc[mi][ni], 0, 0, 0);
    __syncthreads();
    buf ^= 1;
  }

  const int m0 = mt * 128 + wr * 64, n0 = ntl * 128 + wc * 64;
#pragma unroll
  for (int ni = 0; ni < 4; ++ni) {
    int n = n0 + ni * 16 + (lane & 15);
    float bvv = bias[n];
    int h = n >> 6, d = n & 63;
#pragma unroll
    for (int mi = 0; mi < 4; ++mi) {
      int m = m0 + mi * 16 + ((lane >> 4) << 2);
      int b = m >> 11, s = m & 2047;
      if (mode < 2) {
        _Float16* dst = out + (((size_t)(b * 12 + h) * 2048 + s) * 64 + d);
#pragma unroll
        for (int r = 0; r < 4; ++r) dst[(size_t)r * 64] = (_Float16)((acc[mi][ni][r] + bvv) * oscale);
      } else {
        half4_t pk;
#pragma unroll
        for (int r = 0; r < 4; ++r) pk[r] = (_Float16)(acc[mi][ni][r] + bvv);
        *(half4_t*)(out + ((size_t)(b * 12 + h) * 64 + d) * 2048 + s) = pk;
      }
    }
  }
}

// ---------------- flash attention: V-frag preload + split o_sum (R16 + latency cut) --
// grid 768 (XCD decode), 4 waves/block, wave owns 32 q-rows. KVBLK=64, D=64.
// All 16 ds_read_b128 (K+V frags) issue at iter top — counted lgkmcnt lets QK
// start on K while V-reads finish under QK/exp2 (removes the 2nd mid-iter LDS
// latency window). o_sum split into 2 parallel ones-MFMA chains (2-deep tails).
// Mask term rides the QK MFMA as a 5th K-chunk (f16 table). Tile order rotated
// by (blockIdx%3)*11. Fixed softmax reference MREF. Swapped QK^T: D[k][q]=mfma(K,Q);
// lane l: q=l&31, k=(reg&3)+8*(reg>>2)+4*(l>>5). P->f16 via cvt_pkrtz+permlane32_swap.
__global__ __launch_bounds__(256, 3) void flash_attn(
    const _Float16* __restrict__ qb, const _Float16* __restrict__ kbuf,
    const _Float16* __restrict__ vtb, const _Float16* __restrict__ mk16,
    float* __restrict__ out) {
  __shared__ _Float16 Kl[2][64 * 64];
  __shared__ _Float16 Vl[2][64 * 64];

  const int tid = threadIdx.x;
  const int lane = tid & 63, w = tid >> 6;
  const int l31 = lane & 31, hi32 = lane >> 5;

  const int i = blockIdx.x;
  const int bh = (i & 7) + 8 * ((i >> 3) >> 4);
  const int qt = (i >> 3) & 15;
  const int b = bh / 12, h = bh % 12;
  const int q0w = qt * 128 + w * 32;

  const _Float16* Kg = kbuf + (size_t)bh * 2048 * 64;
  const _Float16* Vg = vtb + (size_t)bh * 64 * 2048;
  const _Float16* mkrow = mk16 + (size_t)b * 2048;

  // Q fragments (B-operand, K=16 chunks): qf[c][j] = Q[q0w+l31][c*16 + hi32*8 + j]
  half8 qf[4];
  {
    const _Float16* qp = qb + ((size_t)bh * 2048 + q0w + l31) * 64 + hi32 * 8;
#pragma unroll
    for (int c = 0; c < 4; ++c) qf[c] = *(const half8*)(qp + c * 16);
  }

  auto stageK = [&](int nb, int t) {
#pragma unroll
    for (int it = 0; it < 2; ++it) {
      int ci = tid + it * 256;
      int row = ci >> 3, c = ci & 7;
      int sw = ((c ^ (row & 7)) << 4);
      gld16((const char*)Kg + (size_t)t * 8192 + row * 128 + sw, (char*)&Kl[nb][0] + ci * 16);
    }
  };
  auto stageV = [&](int nb, int t) {
#pragma unroll
    for (int it = 0; it < 2; ++it) {
      int ci = tid + it * 256;
      int row = ci >> 3, c = ci & 7;
      int sw = ((c ^ (row & 7)) << 4);
      gld16((const char*)Vg + (size_t)row * 4096 + t * 128 + sw, (char*)&Vl[nb][0] + ci * 16);
    }
  };

  // loop-invariant fragments/constants
  f32x16 zero16;
#pragma unroll
  for (int r = 0; r < 16; ++r) zero16[r] = 0.f;
  half8 b4 = {};                       // mask B-frag: 1 at k-elem 0 (lanes hi32==0)
  b4[0] = (hi32 == 0) ? (_Float16)1.f : (_Float16)0.f;
  const half8 ones = {(_Float16)1.f, (_Float16)1.f, (_Float16)1.f, (_Float16)1.f,
                      (_Float16)1.f, (_Float16)1.f, (_Float16)1.f, (_Float16)1.f};

  const int phase = (i % 3) * 11;      // cross-block tile-phase decorrelation

  // prologue: K/V of first tile
  stageK(0, phase);
  stageV(0, phase);
  __syncthreads();

  f32x16 o[2], o_sumA, o_sumB;
#pragma unroll
  for (int dt = 0; dt < 2; ++dt)
#pragma unroll
    for (int r = 0; r < 16; ++r) o[dt][r] = 0.f;
#pragma unroll
  for (int r = 0; r < 16; ++r) { o_sumA[r] = 0.f; o_sumB[r] = 0.f; }

  int buf = 0;
  for (int t = 0; t < 32; ++t) {
    const int tc = (phase + t) & 31;
    if (t + 1 < 32) {
      const int tn = (phase + t + 1) & 31;
      stageK(buf ^ 1, tn);
      stageV(buf ^ 1, tn);
    }

    // mask A-frag values for this tile (global f16, issued early)
    _Float16 mv0 = mkrow[tc * 64 + l31];
    _Float16 mv1 = mkrow[tc * 64 + 32 + l31];

    // ---- ALL LDS reads issue here (K for QK; V preloaded for PV) ----
    const char* kb = (const char*)&Kl[buf][0];
    const char* vb = (const char*)&Vl[buf][0];
    half8 kfr[2][4], vfr[2][4];
#pragma unroll
    for (int kt = 0; kt < 2; ++kt) {
      int row = kt * 32 + l31;
      int swz = (row & 7) << 4;
      const char* krow = kb + row * 128;
      const char* vrow = vb + row * 128;
#pragma unroll
      for (int c = 0; c < 4; ++c) {
        int co = (c * 32 + hi32 * 16) ^ swz;
        kfr[kt][c] = *(const half8*)(krow + co);
        vfr[kt][c] = *(const half8*)(vrow + co);
      }
    }

    // QK^T swapped; C chains from zero16; mask-MFMA appended
    f32x16 sc[2];
    __builtin_amdgcn_s_setprio(1);
#pragma unroll
    for (int kt = 0; kt < 2; ++kt) {
      f32x16 z = zero16;
#pragma unroll
      for (int c = 0; c < 4; ++c)
        z = __builtin_amdgcn_mfma_f32_32x32x16_f16(kfr[kt][c], qf[c], z, 0, 0, 0);
      half8 a4 = {};
      a4[0] = (hi32 == 0) ? (kt == 0 ? mv0 : mv1) : (_Float16)0.f;
      z = __builtin_amdgcn_mfma_f32_32x32x16_f16(a4, b4, z, 0, 0, 0);
      sc[kt] = z;
    }
    __builtin_amdgcn_s_setprio(0);

    // exp2 directly on scores (fixed reference)
#pragma unroll
    for (int kt = 0; kt < 2; ++kt)
#pragma unroll
      for (int r = 0; r < 16; ++r)
        sc[kt][r] = __builtin_amdgcn_exp2f(sc[kt][r]);

    // P -> f16 A-frags in-register (R4-verified mapping)
    half8 pa[4];
#pragma unroll
    for (int kt = 0; kt < 2; ++kt)
#pragma unroll
      for (int cc = 0; cc < 2; ++cc) {
        int b0 = cc * 8;
        union { fp16x2 hh; unsigned u; } u01, u23, u45, u67;
        u01.hh = __builtin_amdgcn_cvt_pkrtz(sc[kt][b0 + 0], sc[kt][b0 + 1]);
        u23.hh = __builtin_amdgcn_cvt_pkrtz(sc[kt][b0 + 2], sc[kt][b0 + 3]);
        u45.hh = __builtin_amdgcn_cvt_pkrtz(sc[kt][b0 + 4], sc[kt][b0 + 5]);
        u67.hh = __builtin_amdgcn_cvt_pkrtz(sc[kt][b0 + 6], sc[kt][b0 + 7]);
        u32x2 s1 = __builtin_amdgcn_permlane32_swap(u01.u, u45.u, false, false);
        u32x2 s2 = __builtin_amdgcn_permlane32_swap(u23.u, u67.u, false, false);
        union { unsigned u[4]; half8 hv; } a;
        a.u[0] = s1[0]; a.u[1] = s2[0]; a.u[2] = s1[1]; a.u[3] = s2[1];
        pa[kt * 2 + cc] = a.hv;
      }

    // PV from preloaded V regs; row-sum on 2 parallel ones-MFMA chains
    __builtin_amdgcn_s_setprio(1);
#pragma unroll
    for (int dt = 0; dt < 2; ++dt)
#pragma unroll
      for (int ch = 0; ch < 4; ++ch)
        o[dt] = __builtin_amdgcn_mfma_f32_32x32x16_f16(pa[ch], vfr[dt][ch], o[dt], 0, 0, 0);
    o_sumA = __builtin_amdgcn_mfma_f32_32x32x16_f16(pa[0], ones, o_sumA, 0, 0, 0);
    o_sumB = __builtin_amdgcn_mfma_f32_32x32x16_f16(pa[1], ones, o_sumB, 0, 0, 0);
    o_sumA = __builtin_amdgcn_mfma_f32_32x32x16_f16(pa[2], ones, o_sumA, 0, 0, 0);
    o_sumB = __builtin_amdgcn_mfma_f32_32x32x16_f16(pa[3], ones, o_sumB, 0, 0, 0);
    __builtin_amdgcn_s_setprio(0);

    __syncthreads();  // K/V DMA(next) landed; all waves done reading buf
    buf ^= 1;
  }

  // epilogue: lane's o_sum[r] is the denominator for its own row qrow(r)
#pragma unroll
  for (int r = 0; r < 16; ++r) {
    int qrow = (r & 3) + 8 * (r >> 2) + 4 * hi32;
    float iq = 1.f / (o_sumA[r] + o_sumB[r]);
    float* op = out + ((size_t)(b * 2048) + q0w + qrow) * 768 + h * 64 + l31;
    op[0] = o[0][r] * iq;
    op[32] = o[1][r] * iq;
  }
}

extern "C" void kernel_launch(void* const* d_in, const int* in_sizes, int n_in,
                              void* d_out, int out_size, void* d_ws, size_t ws_size,
                              hipStream_t stream) {
  const float* hidden = (const float*)d_in[0];
  const float* mask = (const float*)d_in[1];
  const float* Wq = (const float*)d_in[2];
  const float* bq = (const float*)d_in[3];
  const float* Wk = (const float*)d_in[4];
  const float* bk = (const float*)d_in[5];
  const float* Wv = (const float*)d_in[6];
  const float* bv = (const float*)d_in[7];
  // d_in[8] (head_bias) is constant over the softmax axis -> exactly cancels; unused.
  float* out = (float*)d_out;

  char* ws = (char*)d_ws;
  _Float16* hb   = (_Float16*)(ws);               // [8192][768] f16 (dead after gemm)
  _Float16* wqb  = (_Float16*)(ws + 12582912);
  _Float16* wkb  = (_Float16*)(ws + 13762560);
  _Float16* wvb  = (_Float16*)(ws + 14942208);
  _Float16* qbuf = (_Float16*)(ws + 16121856);    // [48][2048][64]
  _Float16* kbuf = (_Float16*)(ws + 28704768);    // [48][2048][64]
  _Float16* vtb  = (_Float16*)(ws + 41287680);    // [48][64][2048], ends 66453504

  const size_t MK16_OFF = 66453504;
  const bool dedicated = (ws_size >= MK16_OFF + 16384);
  _Float16* mk16 = dedicated ? (_Float16*)(ws + MK16_OFF) : (_Float16*)(ws);  // else hb region

  prep_all<<<dim3(2048), dim3(256), 0, stream>>>(hidden, Wq, Wk, Wv, mask,
                                                 hb, wqb, wkb, wvb, mk16,
                                                 dedicated ? 1 : 0);
  qkv_gemm<<<dim3(64, 6, 3), dim3(256), 0, stream>>>(hb, wqb, wkb, wvb, bq, bk, bv,
                                                     qbuf, kbuf, vtb);
  if (!dedicated)
    prep_mask16<<<dim3(32), dim3(256), 0, stream>>>(mask, mk16, 8192);
  flash_attn<<<dim3(768), dim3(256), 0, stream>>>(qbuf, kbuf, vtb, mk16, out);
}

// Round 18
// 142.876 us; speedup vs baseline: 1.4158x; 1.4158x over previous
//
#include <hip/hip_runtime.h>

#define LOG2E 1.44269504088896340736f
#define QSCALE 0.18033688011112042f  // 0.125 * LOG2E, folded into Q at projection
#define MREF 16.0f                   // fixed softmax reference (log2 domain)

typedef _Float16 half8 __attribute__((ext_vector_type(8)));
typedef _Float16 half4_t __attribute__((ext_vector_type(4)));
typedef __fp16 fp16x2 __attribute__((ext_vector_type(2)));
typedef float f32x4 __attribute__((ext_vector_type(4)));
typedef float f32x16 __attribute__((ext_vector_type(16)));
typedef unsigned int u32x2 __attribute__((ext_vector_type(2)));

__device__ __forceinline__ void gld16(const void* g, void* l) {
  __builtin_amdgcn_global_load_lds(
      (const __attribute__((address_space(1))) void*)g,
      (__attribute__((address_space(3))) void*)l, 16, 0, 0);
}

// ---------------- merged prep: f32->f16 cvt (hidden+W) + f16 mask table, 1 launch ---
// mask table: mk16[k] = (f16)((1-mask[k])*(-10000*log2e) - MREF). mask=1 -> -16 exact.
__global__ void prep_all(const float* __restrict__ hidden, const float* __restrict__ Wq,
                         const float* __restrict__ Wk, const float* __restrict__ Wv,
                         const float* __restrict__ mask,
                         _Float16* __restrict__ hb, _Float16* __restrict__ wqb,
                         _Float16* __restrict__ wkb, _Float16* __restrict__ wvb,
                         _Float16* __restrict__ mk16, int do_mask) {
  const int NH = 1572864, NW = 147456, NM = 2048;  // f32x4 element counts
  const int total = NH + 3 * NW + (do_mask ? NM : 0);
  int i = blockIdx.x * blockDim.x + threadIdx.x;
  int st = gridDim.x * blockDim.x;
  for (int idx = i; idx < total; idx += st) {
    if (idx < NH + 3 * NW) {
      const float* src; _Float16* dst; int off;
      if (idx < NH) { src = hidden; dst = hb; off = idx; }
      else if (idx < NH + NW) { src = Wq; dst = wqb; off = idx - NH; }
      else if (idx < NH + 2 * NW) { src = Wk; dst = wkb; off = idx - NH - NW; }
      else { src = Wv; dst = wvb; off = idx - NH - 2 * NW; }
      float4 v = reinterpret_cast<const float4*>(src)[off];
      half4_t hh;
      hh[0] = (_Float16)v.x; hh[1] = (_Float16)v.y; hh[2] = (_Float16)v.z; hh[3] = (_Float16)v.w;
      reinterpret_cast<half4_t*>(dst)[off] = hh;
    } else {
      int off = idx - NH - 3 * NW;
      float4 v = reinterpret_cast<const float4*>(mask)[off];
      half4_t hh;
      hh[0] = (_Float16)((1.0f - v.x) * (-10000.0f * LOG2E) - MREF);
      hh[1] = (_Float16)((1.0f - v.y) * (-10000.0f * LOG2E) - MREF);
      hh[2] = (_Float16)((1.0f - v.z) * (-10000.0f * LOG2E) - MREF);
      hh[3] = (_Float16)((1.0f - v.w) * (-10000.0f * LOG2E) - MREF);
      reinterpret_cast<half4_t*>(mk16)[off] = hh;
    }
  }
}

// fallback (only if ws_size too small for the dedicated mk16 region): runs after gemm
__global__ void prep_mask16(const float* __restrict__ mask, _Float16* __restrict__ mk16, int n) {
  int i = blockIdx.x * blockDim.x + threadIdx.x;
  if (i < n) mk16[i] = (_Float16)((1.0f - mask[i]) * (-10000.0f * LOG2E) - MREF);
}

// ---------------- QKV projection GEMM (XCD-swizzled mt; verified R15) ----------------
// mode 0: q (pre-scaled by QSCALE) -> [b][h][s][d]; mode 1: k -> same; mode 2: v -> [b][h][d][s]
__global__ __launch_bounds__(256) void qkv_gemm(
    const _Float16* __restrict__ X,
    const _Float16* __restrict__ Wq, const _Float16* __restrict__ Wk, const _Float16* __restrict__ Wv,
    const float* __restrict__ bq, const float* __restrict__ bk, const float* __restrict__ bv,
    _Float16* __restrict__ qo, _Float16* __restrict__ ko, _Float16* __restrict__ vo) {
  __shared__ _Float16 Al[2][128 * 32];
  __shared__ _Float16 Bl[2][128 * 32];
  const int tid = threadIdx.x;
  const int lane = tid & 63, w = tid >> 6;
  const int wr = w >> 1, wc = w & 1;
  const int bx = blockIdx.x;
  const int mt = (bx & 7) * 8 + (bx >> 3);  // bijective on [0,64): XCD keeps its X-panels
  const int ntl = blockIdx.y, mode = blockIdx.z;
  const _Float16* W = (mode == 0) ? Wq : (mode == 1) ? Wk : Wv;
  const float* bias = (mode == 0) ? bq : (mode == 1) ? bk : bv;
  _Float16* out = (mode == 0) ? qo : (mode == 1) ? ko : vo;
  const float oscale = (mode == 0) ? QSCALE : 1.0f;

  const _Float16* Xb = X + (size_t)mt * 128 * 768;
  const _Float16* Wb = W + (size_t)ntl * 128 * 768;

  const f32x4 zero4 = {0.f, 0.f, 0.f, 0.f};
  f32x4 acc[4][4];
#pragma unroll
  for (int i = 0; i < 4; ++i)
#pragma unroll
    for (int j = 0; j < 4; ++j) acc[i][j] = zero4;

  auto stage = [&](int bufi, int kt) {
#pragma unroll
    for (int it = 0; it < 2; ++it) {
      int ci = tid + it * 256;
      int row = ci >> 2, c = ci & 3;
      int sw = ((c ^ ((row >> 1) & 3)) << 4);
      gld16((const char*)(Xb + row * 768) + kt * 64 + sw, (char*)&Al[bufi][0] + ci * 16);
      gld16((const char*)(Wb + row * 768) + kt * 64 + sw, (char*)&Bl[bufi][0] + ci * 16);
    }
  };

  stage(0, 0);
  __syncthreads();
  int buf = 0;
  for (int kt = 0; kt < 24; ++kt) {
    if (kt + 1 < 24) stage(buf ^ 1, kt + 1);
    half8 af[4], bf[4];
#pragma unroll
    for (int mi = 0; mi < 4; ++mi) {
      int row = wr * 64 + mi * 16 + (lane & 15);
      int cc = (lane >> 4) ^ ((row >> 1) & 3);
      af[mi] = *(const half8*)((const char*)&Al[buf][0] + row * 64 + cc * 16);
    }
#pragma unroll
    for (int ni = 0; ni < 4; ++ni) {
      int row = wc * 64 + ni * 16 + (lane & 15);
      int cc = (lane >> 4) ^ ((row >> 1) & 3);
      bf[ni] = *(const half8*)((const char*)&Bl[buf][0] + row * 64 + cc * 16);
    }
#pragma unroll
    for (int mi = 0; mi < 4; ++mi)
#pragma unroll
      for (int ni = 0; ni < 4; ++ni)
        acc[mi][ni] = __builtin_amdgcn_mfma_f32_16x16x32_f16(af[mi], bf[ni], acc[mi][ni], 0, 0, 0);
    __syncthreads();
    buf ^= 1;
  }

  const int m0 = mt * 128 + wr * 64, n0 = ntl * 128 + wc * 64;
#pragma unroll
  for (int ni = 0; ni < 4; ++ni) {
    int n = n0 + ni * 16 + (lane & 15);
    float bvv = bias[n];
    int h = n >> 6, d = n & 63;
#pragma unroll
    for (int mi = 0; mi < 4; ++mi) {
      int m = m0 + mi * 16 + ((lane >> 4) << 2);
      int b = m >> 11, s = m & 2047;
      if (mode < 2) {
        _Float16* dst = out + (((size_t)(b * 12 + h) * 2048 + s) * 64 + d);
#pragma unroll
        for (int r = 0; r < 4; ++r) dst[(size_t)r * 64] = (_Float16)((acc[mi][ni][r] + bvv) * oscale);
      } else {
        half4_t pk;
#pragma unroll
        for (int r = 0; r < 4; ++r) pk[r] = (_Float16)(acc[mi][ni][r] + bvv);
        *(half4_t*)(out + ((size_t)(b * 12 + h) * 64 + d) * 2048 + s) = pk;
      }
    }
  }
}

// ---------------- flash attention: R16 champion, byte-identical ----------------
// grid 768 (XCD decode), 4 waves/block, wave owns 32 q-rows. KVBLK=64, D=64.
// K/V staged via coalesced global_load_lds (dbuf). Fixed softmax reference MREF.
// Mask term rides the QK MFMA as a 5th K-chunk (f16 table loads). Tile order
// rotated by (blockIdx%3)*11. Row-sum rides the matrix pipe (o_sum = P x ones).
// Swapped QK^T: D[k][q]=mfma(K,Q); lane l: q=l&31, k=(reg&3)+8*(reg>>2)+4*(l>>5).
// P->f16 A-frags via cvt_pkrtz+permlane32_swap (R4-verified mapping).
__global__ __launch_bounds__(256) void flash_attn(
    const _Float16* __restrict__ qb, const _Float16* __restrict__ kbuf,
    const _Float16* __restrict__ vtb, const _Float16* __restrict__ mk16,
    float* __restrict__ out) {
  __shared__ _Float16 Kl[2][64 * 64];
  __shared__ _Float16 Vl[2][64 * 64];

  const int tid = threadIdx.x;
  const int lane = tid & 63, w = tid >> 6;
  const int l31 = lane & 31, hi32 = lane >> 5;

  const int i = blockIdx.x;
  const int bh = (i & 7) + 8 * ((i >> 3) >> 4);
  const int qt = (i >> 3) & 15;
  const int b = bh / 12, h = bh % 12;
  const int q0w = qt * 128 + w * 32;

  const _Float16* Kg = kbuf + (size_t)bh * 2048 * 64;
  const _Float16* Vg = vtb + (size_t)bh * 64 * 2048;
  const _Float16* mkrow = mk16 + (size_t)b * 2048;

  // Q fragments (B-operand, K=16 chunks): qf[c][j] = Q[q0w+l31][c*16 + hi32*8 + j]
  half8 qf[4];
  {
    const _Float16* qp = qb + ((size_t)bh * 2048 + q0w + l31) * 64 + hi32 * 8;
#pragma unroll
    for (int c = 0; c < 4; ++c) qf[c] = *(const half8*)(qp + c * 16);
  }

  auto stageK = [&](int nb, int t) {
#pragma unroll
    for (int it = 0; it < 2; ++it) {
      int ci = tid + it * 256;
      int row = ci >> 3, c = ci & 7;
      int sw = ((c ^ (row & 7)) << 4);
      gld16((const char*)Kg + (size_t)t * 8192 + row * 128 + sw, (char*)&Kl[nb][0] + ci * 16);
    }
  };
  auto stageV = [&](int nb, int t) {
#pragma unroll
    for (int it = 0; it < 2; ++it) {
      int ci = tid + it * 256;
      int row = ci >> 3, c = ci & 7;
      int sw = ((c ^ (row & 7)) << 4);
      gld16((const char*)Vg + (size_t)row * 4096 + t * 128 + sw, (char*)&Vl[nb][0] + ci * 16);
    }
  };

  // loop-invariant fragments/constants
  f32x16 zero16;
#pragma unroll
  for (int r = 0; r < 16; ++r) zero16[r] = 0.f;
  half8 b4 = {};                       // mask B-frag: 1 at k-elem 0 (lanes hi32==0)
  b4[0] = (hi32 == 0) ? (_Float16)1.f : (_Float16)0.f;
  const half8 ones = {(_Float16)1.f, (_Float16)1.f, (_Float16)1.f, (_Float16)1.f,
                      (_Float16)1.f, (_Float16)1.f, (_Float16)1.f, (_Float16)1.f};

  const int phase = (i % 3) * 11;      // cross-block tile-phase decorrelation

  // prologue: K/V of first tile
  stageK(0, phase);
  stageV(0, phase);
  __syncthreads();

  f32x16 o[2], o_sum;
#pragma unroll
  for (int dt = 0; dt < 2; ++dt)
#pragma unroll
    for (int r = 0; r < 16; ++r) o[dt][r] = 0.f;
#pragma unroll
  for (int r = 0; r < 16; ++r) o_sum[r] = 0.f;

  int buf = 0;
  for (int t = 0; t < 32; ++t) {
    const int tc = (phase + t) & 31;
    if (t + 1 < 32) {
      const int tn = (phase + t + 1) & 31;
      stageK(buf ^ 1, tn);
      stageV(buf ^ 1, tn);
    }

    // mask A-frag values for this tile (issued early; consumed at QK chain end)
    _Float16 mv0 = mkrow[tc * 64 + l31];
    _Float16 mv1 = mkrow[tc * 64 + 32 + l31];

    // QK^T swapped; C chains from zero16; mask-MFMA appended (latency covered)
    const char* kb = (const char*)&Kl[buf][0];
    f32x16 sc[2];
    __builtin_amdgcn_s_setprio(1);
#pragma unroll
    for (int kt = 0; kt < 2; ++kt) {
      int row = kt * 32 + l31;
      const char* krow = kb + row * 128;
      int swz = (row & 7) << 4;
      f32x16 z = zero16;
#pragma unroll
      for (int c = 0; c < 4; ++c) {
        half8 ka = *(const half8*)(krow + ((c * 32 + hi32 * 16) ^ swz));
        z = __builtin_amdgcn_mfma_f32_32x32x16_f16(ka, qf[c], z, 0, 0, 0);
      }
      half8 a4 = {};
      a4[0] = (hi32 == 0) ? (kt == 0 ? mv0 : mv1) : (_Float16)0.f;
      z = __builtin_amdgcn_mfma_f32_32x32x16_f16(a4, b4, z, 0, 0, 0);
      sc[kt] = z;
    }
    __builtin_amdgcn_s_setprio(0);

    // exp2 directly on scores (fixed reference)
#pragma unroll
    for (int kt = 0; kt < 2; ++kt)
#pragma unroll
      for (int r = 0; r < 16; ++r)
        sc[kt][r] = __builtin_amdgcn_exp2f(sc[kt][r]);

    // P -> f16 A-frags in-register (R4-verified mapping)
    half8 pa[4];
#pragma unroll
    for (int kt = 0; kt < 2; ++kt)
#pragma unroll
      for (int cc = 0; cc < 2; ++cc) {
        int b0 = cc * 8;
        union { fp16x2 hh; unsigned u; } u01, u23, u45, u67;
        u01.hh = __builtin_amdgcn_cvt_pkrtz(sc[kt][b0 + 0], sc[kt][b0 + 1]);
        u23.hh = __builtin_amdgcn_cvt_pkrtz(sc[kt][b0 + 2], sc[kt][b0 + 3]);
        u45.hh = __builtin_amdgcn_cvt_pkrtz(sc[kt][b0 + 4], sc[kt][b0 + 5]);
        u67.hh = __builtin_amdgcn_cvt_pkrtz(sc[kt][b0 + 6], sc[kt][b0 + 7]);
        u32x2 s1 = __builtin_amdgcn_permlane32_swap(u01.u, u45.u, false, false);
        u32x2 s2 = __builtin_amdgcn_permlane32_swap(u23.u, u67.u, false, false);
        union { unsigned u[4]; half8 hv; } a;
        a.u[0] = s1[0]; a.u[1] = s2[0]; a.u[2] = s1[1]; a.u[3] = s2[1];
        pa[kt * 2 + cc] = a.hv;
      }

    // PV: o[q][d] += P[q][k] * V[k][d]; V from LDS (V^T rows, swizzled).
    // Row-sum rides the matrix pipe: o_sum = P x ones.
    const char* vb = (const char*)&Vl[buf][0];
    __builtin_amdgcn_s_setprio(1);
#pragma unroll
    for (int dt = 0; dt < 2; ++dt) {
      int row = dt * 32 + l31;
      const char* vrow = vb + row * 128;
      int swz = (row & 7) << 4;
#pragma unroll
      for (int ch = 0; ch < 4; ++ch) {
        half8 vbf = *(const half8*)(vrow + ((ch * 32 + hi32 * 16) ^ swz));
        o[dt] = __builtin_amdgcn_mfma_f32_32x32x16_f16(pa[ch], vbf, o[dt], 0, 0, 0);
      }
    }
#pragma unroll
    for (int ch = 0; ch < 4; ++ch)
      o_sum = __builtin_amdgcn_mfma_f32_32x32x16_f16(pa[ch], ones, o_sum, 0, 0, 0);
    __builtin_amdgcn_s_setprio(0);

    __syncthreads();  // K/V DMA(next) landed; all waves done reading buf
    buf ^= 1;
  }

  // epilogue: lane's o_sum[r] is the denominator for its own row qrow(r) — no shuffles
#pragma unroll
  for (int r = 0; r < 16; ++r) {
    int qrow = (r & 3) + 8 * (r >> 2) + 4 * hi32;
    float iq = 1.f / o_sum[r];
    float* op = out + ((size_t)(b * 2048) + q0w + qrow) * 768 + h * 64 + l31;
    op[0] = o[0][r] * iq;
    op[32] = o[1][r] * iq;
  }
}

extern "C" void kernel_launch(void* const* d_in, const int* in_sizes, int n_in,
                              void* d_out, int out_size, void* d_ws, size_t ws_size,
                              hipStream_t stream) {
  const float* hidden = (const float*)d_in[0];
  const float* mask = (const float*)d_in[1];
  const float* Wq = (const float*)d_in[2];
  const float* bq = (const float*)d_in[3];
  const float* Wk = (const float*)d_in[4];
  const float* bk = (const float*)d_in[5];
  const float* Wv = (const float*)d_in[6];
  const float* bv = (const float*)d_in[7];
  // d_in[8] (head_bias) is constant over the softmax axis -> exactly cancels; unused.
  float* out = (float*)d_out;

  char* ws = (char*)d_ws;
  _Float16* hb   = (_Float16*)(ws);               // [8192][768] f16 (dead after gemm)
  _Float16* wqb  = (_Float16*)(ws + 12582912);
  _Float16* wkb  = (_Float16*)(ws + 13762560);
  _Float16* wvb  = (_Float16*)(ws + 14942208);
  _Float16* qbuf = (_Float16*)(ws + 16121856);    // [48][2048][64]
  _Float16* kbuf = (_Float16*)(ws + 28704768);    // [48][2048][64]
  _Float16* vtb  = (_Float16*)(ws + 41287680);    // [48][64][2048], ends 66453504

  const size_t MK16_OFF = 66453504;
  const bool dedicated = (ws_size >= MK16_OFF + 16384);
  _Float16* mk16 = dedicated ? (_Float16*)(ws + MK16_OFF) : (_Float16*)(ws);  // else hb region

  prep_all<<<dim3(2048), dim3(256), 0, stream>>>(hidden, Wq, Wk, Wv, mask,
                                                 hb, wqb, wkb, wvb, mk16,
                                                 dedicated ? 1 : 0);
  qkv_gemm<<<dim3(64, 6, 3), dim3(256), 0, stream>>>(hb, wqb, wkb, wvb, bq, bk, bv,
                                                     qbuf, kbuf, vtb);
  if (!dedicated)
    prep_mask16<<<dim3(32), dim3(256), 0, stream>>>(mask, mk16, 8192);
  flash_attn<<<dim3(768), dim3(256), 0, stream>>>(qbuf, kbuf, vtb, mk16, out);
}

// Round 19
// 139.579 us; speedup vs baseline: 1.4492x; 1.0236x over previous
//
#include <hip/hip_runtime.h>

#define LOG2E 1.44269504088896340736f
#define QSCALE 0.18033688011112042f  // 0.125 * LOG2E, folded into Q at projection
#define MREF 16.0f                   // fixed softmax reference (log2 domain)

typedef _Float16 half8 __attribute__((ext_vector_type(8)));
typedef _Float16 half4_t __attribute__((ext_vector_type(4)));
typedef __fp16 fp16x2 __attribute__((ext_vector_type(2)));
typedef float f32x4 __attribute__((ext_vector_type(4)));
typedef float f32x16 __attribute__((ext_vector_type(16)));
typedef unsigned int u32x2 __attribute__((ext_vector_type(2)));

__device__ __forceinline__ void gld16(const void* g, void* l) {
  __builtin_amdgcn_global_load_lds(
      (const __attribute__((address_space(1))) void*)g,
      (__attribute__((address_space(3))) void*)l, 16, 0, 0);
}

// ---------------- merged prep: f32->f16 cvt (hidden+W) + f16 mask table, 1 launch ---
// mask table: mk16[k] = (f16)((1-mask[k])*(-10000*log2e) - MREF). mask=1 -> -16 exact.
__global__ void prep_all(const float* __restrict__ hidden, const float* __restrict__ Wq,
                         const float* __restrict__ Wk, const float* __restrict__ Wv,
                         const float* __restrict__ mask,
                         _Float16* __restrict__ hb, _Float16* __restrict__ wqb,
                         _Float16* __restrict__ wkb, _Float16* __restrict__ wvb,
                         _Float16* __restrict__ mk16, int do_mask) {
  const int NH = 1572864, NW = 147456, NM = 2048;  // f32x4 element counts
  const int total = NH + 3 * NW + (do_mask ? NM : 0);
  int i = blockIdx.x * blockDim.x + threadIdx.x;
  int st = gridDim.x * blockDim.x;
  for (int idx = i; idx < total; idx += st) {
    if (idx < NH + 3 * NW) {
      const float* src; _Float16* dst; int off;
      if (idx < NH) { src = hidden; dst = hb; off = idx; }
      else if (idx < NH + NW) { src = Wq; dst = wqb; off = idx - NH; }
      else if (idx < NH + 2 * NW) { src = Wk; dst = wkb; off = idx - NH - NW; }
      else { src = Wv; dst = wvb; off = idx - NH - 2 * NW; }
      float4 v = reinterpret_cast<const float4*>(src)[off];
      half4_t hh;
      hh[0] = (_Float16)v.x; hh[1] = (_Float16)v.y; hh[2] = (_Float16)v.z; hh[3] = (_Float16)v.w;
      reinterpret_cast<half4_t*>(dst)[off] = hh;
    } else {
      int off = idx - NH - 3 * NW;
      float4 v = reinterpret_cast<const float4*>(mask)[off];
      half4_t hh;
      hh[0] = (_Float16)((1.0f - v.x) * (-10000.0f * LOG2E) - MREF);
      hh[1] = (_Float16)((1.0f - v.y) * (-10000.0f * LOG2E) - MREF);
      hh[2] = (_Float16)((1.0f - v.z) * (-10000.0f * LOG2E) - MREF);
      hh[3] = (_Float16)((1.0f - v.w) * (-10000.0f * LOG2E) - MREF);
      reinterpret_cast<half4_t*>(mk16)[off] = hh;
    }
  }
}

// fallback (only if ws_size too small for the dedicated mk16 region): runs after gemm
__global__ void prep_mask16(const float* __restrict__ mask, _Float16* __restrict__ mk16, int n) {
  int i = blockIdx.x * blockDim.x + threadIdx.x;
  if (i < n) mk16[i] = (_Float16)((1.0f - mask[i]) * (-10000.0f * LOG2E) - MREF);
}

// ---------------- QKV projection GEMM (XCD-swizzled mt; verified R15) ----------------
// mode 0: q (pre-scaled by QSCALE) -> [b][h][s][d]; mode 1: k -> same; mode 2: v -> [b][h][d][s]
__global__ __launch_bounds__(256) void qkv_gemm(
    const _Float16* __restrict__ X,
    const _Float16* __restrict__ Wq, const _Float16* __restrict__ Wk, const _Float16* __restrict__ Wv,
    const float* __restrict__ bq, const float* __restrict__ bk, const float* __restrict__ bv,
    _Float16* __restrict__ qo, _Float16* __restrict__ ko, _Float16* __restrict__ vo) {
  __shared__ _Float16 Al[2][128 * 32];
  __shared__ _Float16 Bl[2][128 * 32];
  const int tid = threadIdx.x;
  const int lane = tid & 63, w = tid >> 6;
  const int wr = w >> 1, wc = w & 1;
  const int bx = blockIdx.x;
  const int mt = (bx & 7) * 8 + (bx >> 3);  // bijective on [0,64): XCD keeps its X-panels
  const int ntl = blockIdx.y, mode = blockIdx.z;
  const _Float16* W = (mode == 0) ? Wq : (mode == 1) ? Wk : Wv;
  const float* bias = (mode == 0) ? bq : (mode == 1) ? bk : bv;
  _Float16* out = (mode == 0) ? qo : (mode == 1) ? ko : vo;
  const float oscale = (mode == 0) ? QSCALE : 1.0f;

  const _Float16* Xb = X + (size_t)mt * 128 * 768;
  const _Float16* Wb = W + (size_t)ntl * 128 * 768;

  const f32x4 zero4 = {0.f, 0.f, 0.f, 0.f};
  f32x4 acc[4][4];
#pragma unroll
  for (int i = 0; i < 4; ++i)
#pragma unroll
    for (int j = 0; j < 4; ++j) acc[i][j] = zero4;

  auto stage = [&](int bufi, int kt) {
#pragma unroll
    for (int it = 0; it < 2; ++it) {
      int ci = tid + it * 256;
      int row = ci >> 2, c = ci & 3;
      int sw = ((c ^ ((row >> 1) & 3)) << 4);
      gld16((const char*)(Xb + row * 768) + kt * 64 + sw, (char*)&Al[bufi][0] + ci * 16);
      gld16((const char*)(Wb + row * 768) + kt * 64 + sw, (char*)&Bl[bufi][0] + ci * 16);
    }
  };

  stage(0, 0);
  __syncthreads();
  int buf = 0;
  for (int kt = 0; kt < 24; ++kt) {
    if (kt + 1 < 24) stage(buf ^ 1, kt + 1);
    half8 af[4], bf[4];
#pragma unroll
    for (int mi = 0; mi < 4; ++mi) {
      int row = wr * 64 + mi * 16 + (lane & 15);
      int cc = (lane >> 4) ^ ((row >> 1) & 3);
      af[mi] = *(const half8*)((const char*)&Al[buf][0] + row * 64 + cc * 16);
    }
#pragma unroll
    for (int ni = 0; ni < 4; ++ni) {
      int row = wc * 64 + ni * 16 + (lane & 15);
      int cc = (lane >> 4) ^ ((row >> 1) & 3);
      bf[ni] = *(const half8*)((const char*)&Bl[buf][0] + row * 64 + cc * 16);
    }
#pragma unroll
    for (int mi = 0; mi < 4; ++mi)
#pragma unroll
      for (int ni = 0; ni < 4; ++ni)
        acc[mi][ni] = __builtin_amdgcn_mfma_f32_16x16x32_f16(af[mi], bf[ni], acc[mi][ni], 0, 0, 0);
    __syncthreads();
    buf ^= 1;
  }

  const int m0 = mt * 128 + wr * 64, n0 = ntl * 128 + wc * 64;
#pragma unroll
  for (int ni = 0; ni < 4; ++ni) {
    int n = n0 + ni * 16 + (lane & 15);
    float bvv = bias[n];
    int h = n >> 6, d = n & 63;
#pragma unroll
    for (int mi = 0; mi < 4; ++mi) {
      int m = m0 + mi * 16 + ((lane >> 4) << 2);
      int b = m >> 11, s = m & 2047;
      if (mode < 2) {
        _Float16* dst = out + (((size_t)(b * 12 + h) * 2048 + s) * 64 + d);
#pragma unroll
        for (int r = 0; r < 4; ++r) dst[(size_t)r * 64] = (_Float16)((acc[mi][ni][r] + bvv) * oscale);
      } else {
        half4_t pk;
#pragma unroll
        for (int r = 0; r < 4; ++r) pk[r] = (_Float16)(acc[mi][ni][r] + bvv);
        *(half4_t*)(out + ((size_t)(b * 12 + h) * 64 + d) * 2048 + s) = pk;
      }
    }
  }
}

// ---------------- flash attention: R16 champion + VALU lsum (R11-verified) ----------
// grid 768 (XCD decode), 4 waves/block, wave owns 32 q-rows. KVBLK=64, D=64.
// K/V staged via coalesced global_load_lds (dbuf). Fixed softmax reference MREF.
// Mask term rides the QK MFMA as a 5th K-chunk (f16 table loads). Tile order
// rotated by (blockIdx%3)*11. Row-sum via 16 parallel VALU accumulators (R11:
// measured 2.5us faster than ones-MFMA; epilogue tree+permlane+shfl is one-time).
// Swapped QK^T: D[k][q]=mfma(K,Q); lane l: q=l&31, k=(reg&3)+8*(reg>>2)+4*(l>>5).
// P->f16 A-frags via cvt_pkrtz+permlane32_swap (R4-verified mapping).
__global__ __launch_bounds__(256) void flash_attn(
    const _Float16* __restrict__ qb, const _Float16* __restrict__ kbuf,
    const _Float16* __restrict__ vtb, const _Float16* __restrict__ mk16,
    float* __restrict__ out) {
  __shared__ _Float16 Kl[2][64 * 64];
  __shared__ _Float16 Vl[2][64 * 64];

  const int tid = threadIdx.x;
  const int lane = tid & 63, w = tid >> 6;
  const int l31 = lane & 31, hi32 = lane >> 5;

  const int i = blockIdx.x;
  const int bh = (i & 7) + 8 * ((i >> 3) >> 4);
  const int qt = (i >> 3) & 15;
  const int b = bh / 12, h = bh % 12;
  const int q0w = qt * 128 + w * 32;

  const _Float16* Kg = kbuf + (size_t)bh * 2048 * 64;
  const _Float16* Vg = vtb + (size_t)bh * 64 * 2048;
  const _Float16* mkrow = mk16 + (size_t)b * 2048;

  // Q fragments (B-operand, K=16 chunks): qf[c][j] = Q[q0w+l31][c*16 + hi32*8 + j]
  half8 qf[4];
  {
    const _Float16* qp = qb + ((size_t)bh * 2048 + q0w + l31) * 64 + hi32 * 8;
#pragma unroll
    for (int c = 0; c < 4; ++c) qf[c] = *(const half8*)(qp + c * 16);
  }

  auto stageK = [&](int nb, int t) {
#pragma unroll
    for (int it = 0; it < 2; ++it) {
      int ci = tid + it * 256;
      int row = ci >> 3, c = ci & 7;
      int sw = ((c ^ (row & 7)) << 4);
      gld16((const char*)Kg + (size_t)t * 8192 + row * 128 + sw, (char*)&Kl[nb][0] + ci * 16);
    }
  };
  auto stageV = [&](int nb, int t) {
#pragma unroll
    for (int it = 0; it < 2; ++it) {
      int ci = tid + it * 256;
      int row = ci >> 3, c = ci & 7;
      int sw = ((c ^ (row & 7)) << 4);
      gld16((const char*)Vg + (size_t)row * 4096 + t * 128 + sw, (char*)&Vl[nb][0] + ci * 16);
    }
  };

  // loop-invariant fragments/constants
  f32x16 zero16;
#pragma unroll
  for (int r = 0; r < 16; ++r) zero16[r] = 0.f;
  half8 b4 = {};                       // mask B-frag: 1 at k-elem 0 (lanes hi32==0)
  b4[0] = (hi32 == 0) ? (_Float16)1.f : (_Float16)0.f;

  const int phase = (i % 3) * 11;      // cross-block tile-phase decorrelation

  // prologue: K/V of first tile
  stageK(0, phase);
  stageV(0, phase);
  __syncthreads();

  f32x16 o[2];
  float lsum[16];
#pragma unroll
  for (int dt = 0; dt < 2; ++dt)
#pragma unroll
    for (int r = 0; r < 16; ++r) o[dt][r] = 0.f;
#pragma unroll
  for (int r = 0; r < 16; ++r) lsum[r] = 0.f;

  int buf = 0;
  for (int t = 0; t < 32; ++t) {
    const int tc = (phase + t) & 31;
    if (t + 1 < 32) {
      const int tn = (phase + t + 1) & 31;
      stageK(buf ^ 1, tn);
      stageV(buf ^ 1, tn);
    }

    // mask A-frag values for this tile (issued early; consumed at QK chain end)
    _Float16 mv0 = mkrow[tc * 64 + l31];
    _Float16 mv1 = mkrow[tc * 64 + 32 + l31];

    // QK^T swapped; C chains from zero16; mask-MFMA appended (latency covered)
    const char* kb = (const char*)&Kl[buf][0];
    f32x16 sc[2];
    __builtin_amdgcn_s_setprio(1);
#pragma unroll
    for (int kt = 0; kt < 2; ++kt) {
      int row = kt * 32 + l31;
      const char* krow = kb + row * 128;
      int swz = (row & 7) << 4;
      f32x16 z = zero16;
#pragma unroll
      for (int c = 0; c < 4; ++c) {
        half8 ka = *(const half8*)(krow + ((c * 32 + hi32 * 16) ^ swz));
        z = __builtin_amdgcn_mfma_f32_32x32x16_f16(ka, qf[c], z, 0, 0, 0);
      }
      half8 a4 = {};
      a4[0] = (hi32 == 0) ? (kt == 0 ? mv0 : mv1) : (_Float16)0.f;
      z = __builtin_amdgcn_mfma_f32_32x32x16_f16(a4, b4, z, 0, 0, 0);
      sc[kt] = z;
    }
    __builtin_amdgcn_s_setprio(0);

    // exp2 directly on scores (fixed reference); 16 parallel row-sum accumulators
#pragma unroll
    for (int kt = 0; kt < 2; ++kt)
#pragma unroll
      for (int r = 0; r < 16; ++r)
        sc[kt][r] = __builtin_amdgcn_exp2f(sc[kt][r]);
#pragma unroll
    for (int r = 0; r < 16; ++r) lsum[r] += sc[0][r] + sc[1][r];

    // P -> f16 A-frags in-register (R4-verified mapping)
    half8 pa[4];
#pragma unroll
    for (int kt = 0; kt < 2; ++kt)
#pragma unroll
      for (int cc = 0; cc < 2; ++cc) {
        int b0 = cc * 8;
        union { fp16x2 hh; unsigned u; } u01, u23, u45, u67;
        u01.hh = __builtin_amdgcn_cvt_pkrtz(sc[kt][b0 + 0], sc[kt][b0 + 1]);
        u23.hh = __builtin_amdgcn_cvt_pkrtz(sc[kt][b0 + 2], sc[kt][b0 + 3]);
        u45.hh = __builtin_amdgcn_cvt_pkrtz(sc[kt][b0 + 4], sc[kt][b0 + 5]);
        u67.hh = __builtin_amdgcn_cvt_pkrtz(sc[kt][b0 + 6], sc[kt][b0 + 7]);
        u32x2 s1 = __builtin_amdgcn_permlane32_swap(u01.u, u45.u, false, false);
        u32x2 s2 = __builtin_amdgcn_permlane32_swap(u23.u, u67.u, false, false);
        union { unsigned u[4]; half8 hv; } a;
        a.u[0] = s1[0]; a.u[1] = s2[0]; a.u[2] = s1[1]; a.u[3] = s2[1];
        pa[kt * 2 + cc] = a.hv;
      }

    // PV: o[q][d] += P[q][k] * V[k][d]; V from LDS (V^T rows, swizzled)
    const char* vb = (const char*)&Vl[buf][0];
    __builtin_amdgcn_s_setprio(1);
#pragma unroll
    for (int dt = 0; dt < 2; ++dt) {
      int row = dt * 32 + l31;
      const char* vrow = vb + row * 128;
      int swz = (row & 7) << 4;
#pragma unroll
      for (int ch = 0; ch < 4; ++ch) {
        half8 vbf = *(const half8*)(vrow + ((ch * 32 + hi32 * 16) ^ swz));
        o[dt] = __builtin_amdgcn_mfma_f32_32x32x16_f16(pa[ch], vbf, o[dt], 0, 0, 0);
      }
    }
    __builtin_amdgcn_s_setprio(0);

    __syncthreads();  // K/V DMA(next) landed; all waves done reading buf
    buf ^= 1;
  }

  // epilogue (R11-verified): reduce lsum once (tree + cross-half permlane), broadcast
  float l_;
  {
#pragma unroll
    for (int s = 8; s >= 1; s >>= 1)
#pragma unroll
      for (int r = 0; r < s; ++r) lsum[r] += lsum[r + s];
    union { float f; unsigned u; } a; a.f = lsum[0];
    u32x2 sw = __builtin_amdgcn_permlane32_swap(a.u, a.u, false, false);
    union { unsigned u; float f; } plo, phi;
    plo.u = sw[0]; phi.u = sw[1];
    l_ = plo.f + phi.f;           // denominator for q = l31 (this lane's column)
  }
  float invl = 1.f / l_;
#pragma unroll
  for (int r = 0; r < 16; ++r) {
    int qrow = (r & 3) + 8 * (r >> 2) + 4 * hi32;
    float iq = __shfl(invl, qrow);  // row qrow's denominator lives in lane l31==qrow
    float* op = out + ((size_t)(b * 2048) + q0w + qrow) * 768 + h * 64 + l31;
    op[0] = o[0][r] * iq;
    op[32] = o[1][r] * iq;
  }
}

extern "C" void kernel_launch(void* const* d_in, const int* in_sizes, int n_in,
                              void* d_out, int out_size, void* d_ws, size_t ws_size,
                              hipStream_t stream) {
  const float* hidden = (const float*)d_in[0];
  const float* mask = (const float*)d_in[1];
  const float* Wq = (const float*)d_in[2];
  const float* bq = (const float*)d_in[3];
  const float* Wk = (const float*)d_in[4];
  const float* bk = (const float*)d_in[5];
  const float* Wv = (const float*)d_in[6];
  const float* bv = (const float*)d_in[7];
  // d_in[8] (head_bias) is constant over the softmax axis -> exactly cancels; unused.
  float* out = (float*)d_out;

  char* ws = (char*)d_ws;
  _Float16* hb   = (_Float16*)(ws);               // [8192][768] f16 (dead after gemm)
  _Float16* wqb  = (_Float16*)(ws + 12582912);
  _Float16* wkb  = (_Float16*)(ws + 13762560);
  _Float16* wvb  = (_Float16*)(ws + 14942208);
  _Float16* qbuf = (_Float16*)(ws + 16121856);    // [48][2048][64]
  _Float16* kbuf = (_Float16*)(ws + 28704768);    // [48][2048][64]
  _Float16* vtb  = (_Float16*)(ws + 41287680);    // [48][64][2048], ends 66453504

  const size_t MK16_OFF = 66453504;
  const bool dedicated = (ws_size >= MK16_OFF + 16384);
  _Float16* mk16 = dedicated ? (_Float16*)(ws + MK16_OFF) : (_Float16*)(ws);  // else hb region

  prep_all<<<dim3(2048), dim3(256), 0, stream>>>(hidden, Wq, Wk, Wv, mask,
                                                 hb, wqb, wkb, wvb, mk16,
                                                 dedicated ? 1 : 0);
  qkv_gemm<<<dim3(64, 6, 3), dim3(256), 0, stream>>>(hb, wqb, wkb, wvb, bq, bk, bv,
                                                     qbuf, kbuf, vtb);
  if (!dedicated)
    prep_mask16<<<dim3(32), dim3(256), 0, stream>>>(mask, mk16, 8192);
  flash_attn<<<dim3(768), dim3(256), 0, stream>>>(qbuf, kbuf, vtb, mk16, out);
}